// Round 3
// baseline (132.695 us; speedup 1.0000x reference)
//
#include <hip/hip_runtime.h>
#include <hip/hip_bf16.h>

#define NKVH 4
#define SEQ 4096
#define BLK 64
#define NW 8
#define NQB 64
#define PP 72

typedef __attribute__((ext_vector_type(8))) short bf16x8;
typedef __attribute__((ext_vector_type(4))) float f32x4;

// round-half-up f32->bf16 pair pack: result = [bf16(hi) : bf16(lo)]
__device__ __forceinline__ unsigned pkbf(unsigned lo, unsigned hi) {
  return __builtin_amdgcn_perm(hi + 0x8000u, lo + 0x8000u, 0x07060302u);
}

__device__ __forceinline__ void gload16(const void* g, void* l) {
  __builtin_amdgcn_global_load_lds(
      (const __attribute__((address_space(1))) void*)g,
      (__attribute__((address_space(3))) void*)l, 16, 0, 0);
}

// ---- pre-pass: K -> bf16 (chunk-swizzled rows), V -> bf16 transposed tiles ----
__global__ __launch_bounds__(256, 4)
void prep_kernel(const float* __restrict__ kp, const float* __restrict__ vp,
                 short* __restrict__ kw, short* __restrict__ vt)
{
  const int ki = blockIdx.x, kvh = blockIdx.y, b = blockIdx.z;
  const size_t base = (((size_t)(b*NKVH + kvh)*SEQ) + (size_t)ki*BLK)*64;
  __shared__ float vlds[64][65];
  const int t = threadIdx.x;
  #pragma unroll
  for (int it = 0; it < 2; ++it) {
    const int task = t + it*256;
    const int n = task >> 3, c8 = task & 7;
    const float* krow = kp + base + n*64 + c8*8;
    float4 a = *(const float4*)krow;
    float4 c = *(const float4*)(krow + 4);
    uint4 o;
    o.x = pkbf(__float_as_uint(a.x), __float_as_uint(a.y));
    o.y = pkbf(__float_as_uint(a.z), __float_as_uint(a.w));
    o.z = pkbf(__float_as_uint(c.x), __float_as_uint(c.y));
    o.w = pkbf(__float_as_uint(c.z), __float_as_uint(c.w));
    *(uint4*)(kw + base + n*64 + ((c8 ^ (n & 7)) * 8)) = o;
    const float* vrow = vp + base + n*64 + c8*8;
    float4 va = *(const float4*)vrow;
    float4 vc = *(const float4*)(vrow + 4);
    vlds[n][c8*8+0] = va.x; vlds[n][c8*8+1] = va.y;
    vlds[n][c8*8+2] = va.z; vlds[n][c8*8+3] = va.w;
    vlds[n][c8*8+4] = vc.x; vlds[n][c8*8+5] = vc.y;
    vlds[n][c8*8+6] = vc.z; vlds[n][c8*8+7] = vc.w;
  }
  __syncthreads();
  #pragma unroll
  for (int it = 0; it < 2; ++it) {
    const int task = t + it*256;
    const int d = task >> 3, cn = task & 7;
    float x0 = vlds[cn*8+0][d], x1 = vlds[cn*8+1][d];
    float x2 = vlds[cn*8+2][d], x3 = vlds[cn*8+3][d];
    float x4 = vlds[cn*8+4][d], x5 = vlds[cn*8+5][d];
    float x6 = vlds[cn*8+6][d], x7 = vlds[cn*8+7][d];
    uint4 o;
    o.x = pkbf(__float_as_uint(x0), __float_as_uint(x1));
    o.y = pkbf(__float_as_uint(x2), __float_as_uint(x3));
    o.z = pkbf(__float_as_uint(x4), __float_as_uint(x5));
    o.w = pkbf(__float_as_uint(x6), __float_as_uint(x7));
    *(uint4*)(vt + base + d*64 + ((cn ^ (d & 7)) * 8)) = o;
  }
}

__global__ __launch_bounds__(512, 4)
void sattn_kernel(const float* __restrict__ qp, const short* __restrict__ kw,
                  const short* __restrict__ vt, const float* __restrict__ alibi,
                  const int* __restrict__ seg, const int* __restrict__ bidx,
                  float* __restrict__ outp)
{
  // XCD-bijective remap: 512 blocks = 8 XCDs x 64; each XCD owns one (b,kvh)
  const int bid = blockIdx.x + NQB*(blockIdx.y + NKVH*blockIdx.z);
  const int nl = (bid & 7)*64 + (bid >> 3);
  const int qb = nl & 63, kvh = (nl >> 6) & 3, b = nl >> 8;

  const int tid = threadIdx.x;
  const int wave = tid >> 6, lane = tid & 63;
  const int lr = lane & 15, lg = lane >> 4;
  const int wr = wave & 3, hp = wave >> 2;

  __shared__ short klds[2][BLK][64];
  __shared__ short vtlds[2][BLK][64];
  __shared__ short plds[8][16][PP];
  __shared__ int   seglds[NW][BLK];

  int kis[NW];
  #pragma unroll
  for (int i = 0; i < NW; ++i) kis[i] = bidx[qb*NW + i];

  const size_t headbase = ((size_t)(b*NKVH + kvh)*SEQ)*64;

  auto STAGE = [&](int buf, int wi) {
    const int ki = kis[wi] < 0 ? 0 : kis[wi];
    const size_t tb = headbase + (size_t)ki*BLK*64;
    gload16((const char*)(kw + tb) + tid*16, (char*)&klds[buf][0][0] + wave*1024);
    gload16((const char*)(vt + tb) + tid*16, (char*)&vtlds[buf][0][0] + wave*1024);
  };

  STAGE(0, 0);
  { // all 8 windows' key segment ids, one coalesced pass
    const int wi = wave, j = lane;
    const int kiw = kis[wi];
    seglds[wi][j] = (kiw < 0) ? -1 : seg[b*SEQ + kiw*BLK + j];
  }

  const int m_glob = qb*BLK + wr*16 + lr;
  const int sq = seg[b*SEQ + m_glob];

  const float LOG2E = 1.4426950408889634f;
  float nslope[2];
  nslope[0] = -alibi[kvh*4 + hp*2 + 0] * LOG2E;
  nslope[1] = -alibi[kvh*4 + hp*2 + 1] * LOG2E;

  // Q into registers (scaled by 0.125*log2e), bf16
  bf16x8 qf[2][2];
  {
    const float qs = 0.125f * LOG2E;
    #pragma unroll
    for (int hh = 0; hh < 2; ++hh) {
      const float* qrow = qp + ((((size_t)b*16 + kvh*4 + hp*2 + hh)*SEQ) + m_glob)*64;
      #pragma unroll
      for (int s = 0; s < 2; ++s) {
        float4 a = *(const float4*)(qrow + s*32 + lg*8);
        float4 c = *(const float4*)(qrow + s*32 + lg*8 + 4);
        union { unsigned u[4]; bf16x8 v; } cv;
        cv.u[0] = pkbf(__float_as_uint(a.x*qs), __float_as_uint(a.y*qs));
        cv.u[1] = pkbf(__float_as_uint(a.z*qs), __float_as_uint(a.w*qs));
        cv.u[2] = pkbf(__float_as_uint(c.x*qs), __float_as_uint(c.y*qs));
        cv.u[3] = pkbf(__float_as_uint(c.z*qs), __float_as_uint(c.w*qs));
        qf[hh][s] = cv.v;
      }
    }
  }

  float mrun[2] = {-1e30f, -1e30f}, lrun[2] = {0.f, 0.f};
  f32x4 oacc[2][4];
  #pragma unroll
  for (int hh = 0; hh < 2; ++hh)
    #pragma unroll
    for (int dt = 0; dt < 4; ++dt) { f32x4 z = {0.f,0.f,0.f,0.f}; oacc[hh][dt] = z; }

  __syncthreads();   // buf0 staged (vmcnt drained), seglds visible

  #pragma unroll
  for (int wi = 0; wi < NW; ++wi) {
    const int cur = wi & 1;
    if (wi + 1 < NW) STAGE(cur ^ 1, wi + 1);   // loads fly during compute
    if (kis[wi] >= 0) {
      const int ki = kis[wi];
      int4 skv[4];
      #pragma unroll
      for (int f = 0; f < 4; ++f) skv[f] = *(const int4*)&seglds[wi][f*16 + lg*4];

      bf16x8 kf[2][4], vf[2][4];
      #pragma unroll
      for (int s = 0; s < 2; ++s)
        #pragma unroll
        for (int f = 0; f < 4; ++f) {
          const int cc = ((s*4 + lg) ^ (lr & 7)) * 8;
          kf[s][f] = *(const bf16x8*)&klds[cur][f*16 + lr][cc];
          vf[s][f] = *(const bf16x8*)&vtlds[cur][f*16 + lr][cc];
        }

      float pdm[4][4];
      #pragma unroll
      for (int f = 0; f < 4; ++f) {
        const int skr[4] = {skv[f].x, skv[f].y, skv[f].z, skv[f].w};
        #pragma unroll
        for (int r = 0; r < 4; ++r) {
          const int n_glob = ki*BLK + f*16 + lg*4 + r;
          const bool dead = (n_glob > m_glob) || (skr[r] != sq);
          pdm[f][r] = dead ? 3.0e34f : (float)(m_glob - n_glob);
        }
      }

      #pragma unroll
      for (int hh = 0; hh < 2; ++hh) {
        f32x4 sacc[4];
        #pragma unroll
        for (int f = 0; f < 4; ++f) { f32x4 z = {0.f,0.f,0.f,0.f}; sacc[f] = z; }
        #pragma unroll
        for (int s = 0; s < 2; ++s)
          #pragma unroll
          for (int f = 0; f < 4; ++f)
            sacc[f] = __builtin_amdgcn_mfma_f32_16x16x32_bf16(kf[s][f], qf[hh][s], sacc[f], 0, 0, 0);

        float mblk = -3.0e38f;
        #pragma unroll
        for (int f = 0; f < 4; ++f)
          #pragma unroll
          for (int r = 0; r < 4; ++r) {
            sacc[f][r] = fmaf(nslope[hh], pdm[f][r], sacc[f][r]);
            mblk = fmaxf(mblk, sacc[f][r]);
          }
        mblk = fmaxf(mblk, __shfl_xor(mblk, 16));
        mblk = fmaxf(mblk, __shfl_xor(mblk, 32));
        const float mnew = fmaxf(mrun[hh], mblk);
        const float corr = __builtin_amdgcn_exp2f(mrun[hh] - mnew);
        mrun[hh] = mnew;

        float psum = 0.f;
        #pragma unroll
        for (int f = 0; f < 4; ++f)
          #pragma unroll
          for (int rp = 0; rp < 2; ++rp) {
            float p0 = __builtin_amdgcn_exp2f(sacc[f][2*rp]   - mnew);
            float p1 = __builtin_amdgcn_exp2f(sacc[f][2*rp+1] - mnew);
            psum += p0 + p1;
            *(unsigned*)&plds[wave][lr][f*16 + lg*4 + 2*rp] =
                pkbf(__float_as_uint(p0), __float_as_uint(p1));
          }
        psum += __shfl_xor(psum, 16);
        psum += __shfl_xor(psum, 32);
        lrun[hh] = lrun[hh]*corr + psum;
        #pragma unroll
        for (int dt = 0; dt < 4; ++dt) oacc[hh][dt] *= corr;

        #pragma unroll
        for (int s = 0; s < 2; ++s) {
          bf16x8 pf = *(const bf16x8*)&plds[wave][lr][s*32 + lg*8];
          #pragma unroll
          for (int dt = 0; dt < 4; ++dt)
            oacc[hh][dt] = __builtin_amdgcn_mfma_f32_16x16x32_bf16(vf[s][dt], pf, oacc[hh][dt], 0, 0, 0);
        }
      }
    }
    __syncthreads();
  }

  #pragma unroll
  for (int hh = 0; hh < 2; ++hh) {
    const float inv = lrun[hh] > 0.f ? 1.f/lrun[hh] : 0.f;
    float* dst = outp + ((((size_t)b*16 + kvh*4 + hp*2 + hh)*SEQ) + m_glob)*64;
    #pragma unroll
    for (int dt = 0; dt < 4; ++dt) {
      float4 o;
      o.x = oacc[hh][dt][0]*inv; o.y = oacc[hh][dt][1]*inv;
      o.z = oacc[hh][dt][2]*inv; o.w = oacc[hh][dt][3]*inv;
      *(float4*)&dst[dt*16 + lg*4] = o;
    }
  }
}

extern "C" void kernel_launch(void* const* d_in, const int* in_sizes, int n_in,
                              void* d_out, int out_size, void* d_ws, size_t ws_size,
                              hipStream_t stream) {
  const float* q    = (const float*)d_in[0];
  const float* k    = (const float*)d_in[1];
  const float* v    = (const float*)d_in[2];
  const float* al   = (const float*)d_in[3];
  const int*   sg   = (const int*)d_in[4];
  const int*   bi   = (const int*)d_in[5];
  short* kws = (short*)d_ws;                              // 4 MiB
  short* vtws = (short*)((char*)d_ws + (size_t)(1u<<22)); // 4 MiB
  dim3 pgrid(NQB, NKVH, 2);
  prep_kernel<<<pgrid, 256, 0, stream>>>(k, v, kws, vtws);
  dim3 grid(NQB, NKVH, 2);
  sattn_kernel<<<grid, 512, 0, stream>>>(q, kws, vtws, al, sg, bi, (float*)d_out);
}

// Round 4
// 54.106 us; speedup vs baseline: 2.4525x; 2.4525x over previous
//
#include <hip/hip_runtime.h>
#include <hip/hip_bf16.h>

#define NKVH 4
#define SEQ 4096
#define BLK 64
#define NW 8
#define NQB 64
#define PP 72

typedef __attribute__((ext_vector_type(8))) short bf16x8;
typedef __attribute__((ext_vector_type(4))) float f32x4;

// round-half-up f32->bf16 pair pack: result = [bf16(hi) : bf16(lo)]
__device__ __forceinline__ unsigned pkbf(unsigned lo, unsigned hi) {
  return __builtin_amdgcn_perm(hi + 0x8000u, lo + 0x8000u, 0x07060302u);
}

__device__ __forceinline__ void gload16(const void* g, void* l) {
  __builtin_amdgcn_global_load_lds(
      (const __attribute__((address_space(1))) void*)g,
      (__attribute__((address_space(3))) void*)l, 16, 0, 0);
}

// ---- pre-pass: K -> bf16 (chunk-swizzled rows), V -> bf16 transposed tiles ----
__global__ __launch_bounds__(256, 4)
void prep_kernel(const float* __restrict__ kp, const float* __restrict__ vp,
                 short* __restrict__ kw, short* __restrict__ vt)
{
  const int ki = blockIdx.x, kvh = blockIdx.y, b = blockIdx.z;
  const size_t base = (((size_t)(b*NKVH + kvh)*SEQ) + (size_t)ki*BLK)*64;
  __shared__ float vlds[64][65];
  const int t = threadIdx.x;
  #pragma unroll
  for (int it = 0; it < 2; ++it) {
    const int task = t + it*256;
    const int n = task >> 3, c8 = task & 7;
    const float* krow = kp + base + n*64 + c8*8;
    float4 a = *(const float4*)krow;
    float4 c = *(const float4*)(krow + 4);
    uint4 o;
    o.x = pkbf(__float_as_uint(a.x), __float_as_uint(a.y));
    o.y = pkbf(__float_as_uint(a.z), __float_as_uint(a.w));
    o.z = pkbf(__float_as_uint(c.x), __float_as_uint(c.y));
    o.w = pkbf(__float_as_uint(c.z), __float_as_uint(c.w));
    *(uint4*)(kw + base + n*64 + ((c8 ^ (n & 7)) * 8)) = o;
    const float* vrow = vp + base + n*64 + c8*8;
    float4 va = *(const float4*)vrow;
    float4 vc = *(const float4*)(vrow + 4);
    vlds[n][c8*8+0] = va.x; vlds[n][c8*8+1] = va.y;
    vlds[n][c8*8+2] = va.z; vlds[n][c8*8+3] = va.w;
    vlds[n][c8*8+4] = vc.x; vlds[n][c8*8+5] = vc.y;
    vlds[n][c8*8+6] = vc.z; vlds[n][c8*8+7] = vc.w;
  }
  __syncthreads();
  #pragma unroll
  for (int it = 0; it < 2; ++it) {
    const int task = t + it*256;
    const int d = task >> 3, cn = task & 7;
    float x0 = vlds[cn*8+0][d], x1 = vlds[cn*8+1][d];
    float x2 = vlds[cn*8+2][d], x3 = vlds[cn*8+3][d];
    float x4 = vlds[cn*8+4][d], x5 = vlds[cn*8+5][d];
    float x6 = vlds[cn*8+6][d], x7 = vlds[cn*8+7][d];
    uint4 o;
    o.x = pkbf(__float_as_uint(x0), __float_as_uint(x1));
    o.y = pkbf(__float_as_uint(x2), __float_as_uint(x3));
    o.z = pkbf(__float_as_uint(x4), __float_as_uint(x5));
    o.w = pkbf(__float_as_uint(x6), __float_as_uint(x7));
    *(uint4*)(vt + base + d*64 + ((cn ^ (d & 7)) * 8)) = o;
  }
}

__global__ __launch_bounds__(512, 2)
void sattn_kernel(const float* __restrict__ qp, const short* __restrict__ kw,
                  const short* __restrict__ vt, const float* __restrict__ alibi,
                  const int* __restrict__ seg, const int* __restrict__ bidx,
                  float* __restrict__ outp)
{
  // XCD-bijective remap: 512 blocks = 8 XCDs x 64; each XCD owns one (b,kvh)
  const int bid = blockIdx.x + NQB*(blockIdx.y + NKVH*blockIdx.z);
  const int nl = (bid & 7)*64 + (bid >> 3);
  const int qb = nl & 63, kvh = (nl >> 6) & 3, b = nl >> 8;

  const int tid = threadIdx.x;
  const int wave = tid >> 6, lane = tid & 63;
  const int lr = lane & 15, lg = lane >> 4;
  const int wr = wave & 3, hp = wave >> 2;

  __shared__ short klds[2][BLK][64];
  __shared__ short vtlds[2][BLK][64];
  __shared__ short plds[8][16][PP];
  __shared__ int   seglds[NW][BLK];

  int kis[NW];
  #pragma unroll
  for (int i = 0; i < NW; ++i) kis[i] = bidx[qb*NW + i];

  const size_t headbase = ((size_t)(b*NKVH + kvh)*SEQ)*64;

  auto STAGE = [&](int buf, int wi) {
    const int ki = kis[wi] < 0 ? 0 : kis[wi];
    const size_t tb = headbase + (size_t)ki*BLK*64;
    gload16((const char*)(kw + tb) + tid*16, (char*)&klds[buf][0][0] + wave*1024);
    gload16((const char*)(vt + tb) + tid*16, (char*)&vtlds[buf][0][0] + wave*1024);
  };

  STAGE(0, 0);
  { // all 8 windows' key segment ids, one coalesced pass
    const int wi = wave, j = lane;
    const int kiw = kis[wi];
    seglds[wi][j] = (kiw < 0) ? -1 : seg[b*SEQ + kiw*BLK + j];
  }

  const int m_glob = qb*BLK + wr*16 + lr;
  const int sq = seg[b*SEQ + m_glob];

  const float LOG2E = 1.4426950408889634f;
  float nslope[2];
  nslope[0] = -alibi[kvh*4 + hp*2 + 0] * LOG2E;
  nslope[1] = -alibi[kvh*4 + hp*2 + 1] * LOG2E;

  // Q into registers (scaled by 0.125*log2e), bf16
  bf16x8 qf[2][2];
  {
    const float qs = 0.125f * LOG2E;
    #pragma unroll
    for (int hh = 0; hh < 2; ++hh) {
      const float* qrow = qp + ((((size_t)b*16 + kvh*4 + hp*2 + hh)*SEQ) + m_glob)*64;
      #pragma unroll
      for (int s = 0; s < 2; ++s) {
        float4 a = *(const float4*)(qrow + s*32 + lg*8);
        float4 c = *(const float4*)(qrow + s*32 + lg*8 + 4);
        union { unsigned u[4]; bf16x8 v; } cv;
        cv.u[0] = pkbf(__float_as_uint(a.x*qs), __float_as_uint(a.y*qs));
        cv.u[1] = pkbf(__float_as_uint(a.z*qs), __float_as_uint(a.w*qs));
        cv.u[2] = pkbf(__float_as_uint(c.x*qs), __float_as_uint(c.y*qs));
        cv.u[3] = pkbf(__float_as_uint(c.z*qs), __float_as_uint(c.w*qs));
        qf[hh][s] = cv.v;
      }
    }
  }

  float mrun[2] = {-1e30f, -1e30f}, lrun[2] = {0.f, 0.f};
  f32x4 oacc[2][4];
  #pragma unroll
  for (int hh = 0; hh < 2; ++hh)
    #pragma unroll
    for (int dt = 0; dt < 4; ++dt) { f32x4 z = {0.f,0.f,0.f,0.f}; oacc[hh][dt] = z; }

  __syncthreads();   // buf0 staged (vmcnt drained), seglds visible

  #pragma unroll
  for (int wi = 0; wi < NW; ++wi) {
    const int cur = wi & 1;
    if (wi + 1 < NW) STAGE(cur ^ 1, wi + 1);   // loads fly during compute
    if (kis[wi] >= 0) {
      const int ki = kis[wi];
      int4 skv[4];
      #pragma unroll
      for (int f = 0; f < 4; ++f) skv[f] = *(const int4*)&seglds[wi][f*16 + lg*4];

      bf16x8 kf[2][4], vf[2][4];
      #pragma unroll
      for (int s = 0; s < 2; ++s)
        #pragma unroll
        for (int f = 0; f < 4; ++f) {
          const int cc = ((s*4 + lg) ^ (lr & 7)) * 8;
          kf[s][f] = *(const bf16x8*)&klds[cur][f*16 + lr][cc];
          vf[s][f] = *(const bf16x8*)&vtlds[cur][f*16 + lr][cc];
        }

      float pdm[4][4];
      #pragma unroll
      for (int f = 0; f < 4; ++f) {
        const int skr[4] = {skv[f].x, skv[f].y, skv[f].z, skv[f].w};
        #pragma unroll
        for (int r = 0; r < 4; ++r) {
          const int n_glob = ki*BLK + f*16 + lg*4 + r;
          const bool dead = (n_glob > m_glob) || (skr[r] != sq);
          pdm[f][r] = dead ? 3.0e34f : (float)(m_glob - n_glob);
        }
      }

      #pragma unroll
      for (int hh = 0; hh < 2; ++hh) {
        f32x4 sacc[4];
        #pragma unroll
        for (int f = 0; f < 4; ++f) { f32x4 z = {0.f,0.f,0.f,0.f}; sacc[f] = z; }
        #pragma unroll
        for (int s = 0; s < 2; ++s)
          #pragma unroll
          for (int f = 0; f < 4; ++f)
            sacc[f] = __builtin_amdgcn_mfma_f32_16x16x32_bf16(kf[s][f], qf[hh][s], sacc[f], 0, 0, 0);

        float mblk = -3.0e38f;
        #pragma unroll
        for (int f = 0; f < 4; ++f)
          #pragma unroll
          for (int r = 0; r < 4; ++r) {
            sacc[f][r] = fmaf(nslope[hh], pdm[f][r], sacc[f][r]);
            mblk = fmaxf(mblk, sacc[f][r]);
          }
        mblk = fmaxf(mblk, __shfl_xor(mblk, 16));
        mblk = fmaxf(mblk, __shfl_xor(mblk, 32));
        const float mnew = fmaxf(mrun[hh], mblk);
        const float corr = __builtin_amdgcn_exp2f(mrun[hh] - mnew);
        mrun[hh] = mnew;

        float psum = 0.f;
        #pragma unroll
        for (int f = 0; f < 4; ++f)
          #pragma unroll
          for (int rp = 0; rp < 2; ++rp) {
            float p0 = __builtin_amdgcn_exp2f(sacc[f][2*rp]   - mnew);
            float p1 = __builtin_amdgcn_exp2f(sacc[f][2*rp+1] - mnew);
            psum += p0 + p1;
            *(unsigned*)&plds[wave][lr][f*16 + lg*4 + 2*rp] =
                pkbf(__float_as_uint(p0), __float_as_uint(p1));
          }
        psum += __shfl_xor(psum, 16);
        psum += __shfl_xor(psum, 32);
        lrun[hh] = lrun[hh]*corr + psum;
        #pragma unroll
        for (int dt = 0; dt < 4; ++dt) oacc[hh][dt] *= corr;

        #pragma unroll
        for (int s = 0; s < 2; ++s) {
          bf16x8 pf = *(const bf16x8*)&plds[wave][lr][s*32 + lg*8];
          #pragma unroll
          for (int dt = 0; dt < 4; ++dt)
            oacc[hh][dt] = __builtin_amdgcn_mfma_f32_16x16x32_bf16(vf[s][dt], pf, oacc[hh][dt], 0, 0, 0);
        }
      }
    }
    __syncthreads();
  }

  #pragma unroll
  for (int hh = 0; hh < 2; ++hh) {
    const float inv = lrun[hh] > 0.f ? 1.f/lrun[hh] : 0.f;
    float* dst = outp + ((((size_t)b*16 + kvh*4 + hp*2 + hh)*SEQ) + m_glob)*64;
    #pragma unroll
    for (int dt = 0; dt < 4; ++dt) {
      float4 o;
      o.x = oacc[hh][dt][0]*inv; o.y = oacc[hh][dt][1]*inv;
      o.z = oacc[hh][dt][2]*inv; o.w = oacc[hh][dt][3]*inv;
      *(float4*)&dst[dt*16 + lg*4] = o;
    }
  }
}

extern "C" void kernel_launch(void* const* d_in, const int* in_sizes, int n_in,
                              void* d_out, int out_size, void* d_ws, size_t ws_size,
                              hipStream_t stream) {
  const float* q    = (const float*)d_in[0];
  const float* k    = (const float*)d_in[1];
  const float* v    = (const float*)d_in[2];
  const float* al   = (const float*)d_in[3];
  const int*   sg   = (const int*)d_in[4];
  const int*   bi   = (const int*)d_in[5];
  short* kws = (short*)d_ws;                              // 4 MiB
  short* vtws = (short*)((char*)d_ws + (size_t)(1u<<22)); // 4 MiB
  dim3 pgrid(NQB, NKVH, 2);
  prep_kernel<<<pgrid, 256, 0, stream>>>(k, v, kws, vtws);
  dim3 grid(NQB, NKVH, 2);
  sattn_kernel<<<grid, 512, 0, stream>>>(q, kws, vtws, al, sg, bi, (float*)d_out);
}